// Round 4
// baseline (18.005 us; speedup 1.0000x reference)
//
#include <hip/hip_runtime.h>

#define BATCH 512
#define NNEG  2048
#define DIM   128
#define PADR  132   // q LDS row stride (floats); bank base 4r, +4g -> 2-way max (free)

// Block: 256 threads (4 waves). Tile: 32 q-rows x 64 tails. Wave w: q-rows [8w,8w+8).
// Lane (dg,tg), dg=lane>>3, tg=lane&7:
//   owns tails {8k+tg, k=0..7} x dims {32m+4dg..32m+4dg+4, m=0..3}  (16 dims/lane)
//   tails come STRAIGHT FROM GLOBAL (L2-hot 32KB tile, no LDS): per load instr
//   (k,m fixed) lanes cover 8 rows x 128B contiguous -> fully coalesced.
//   Two half-dim passes (m={0,1}, then {2,3}) keep tf at 64 VGPRs (no spills).
// q = head + relemb[relid] staged in LDS once (plain padded layout);
//   read 2x b128 per (row,pass): banks 4(r+dg) -> conflict-free 8-lane broadcast.
// Partial sums (8 rows x 8 tails per lane, 16 dims each) combined with a routed
//   xor tree: ds_swizzle imm for masks 8/16, shfl_xor for 32; lane ends with row=dg.

__device__ __forceinline__ float swz8(float v) {
  return __int_as_float(__builtin_amdgcn_ds_swizzle(__float_as_int(v), 0x201F)); // xor 8
}
__device__ __forceinline__ float swz16(float v) {
  return __int_as_float(__builtin_amdgcn_ds_swizzle(__float_as_int(v), 0x401F)); // xor 16
}

__global__ __launch_bounds__(256, 2)
void transe_l1(const float* __restrict__ head,
               const int*   __restrict__ relid,
               const float* __restrict__ tailp,
               const float* __restrict__ relemb,
               float* __restrict__ out) {
  __shared__ float lq[32 * PADR];            // 16,896 B

  const int tid  = threadIdx.x;
  const int bx   = blockIdx.x;
  const int t0   = (bx & 31) * 64;           // 32 tail tiles
  const int b0   = (bx >> 5) * 32;           // 16 batch groups
  const int lane = tid & 63;
  const int w    = tid >> 6;
  const int tg   = lane & 7;
  const int dg   = lane >> 3;

  // ---- issue pass-0 tail loads first (overlap with q staging) ----
  const float* tbase = tailp + (size_t)(t0 + tg) * DIM + 4 * dg;
  float4 tf[8][2];
#pragma unroll
  for (int k = 0; k < 8; ++k) {
#pragma unroll
    for (int j = 0; j < 2; ++j)              // pass 0: m = j
      tf[k][j] = *reinterpret_cast<const float4*>(tbase + (size_t)(8 * k) * DIM + 32 * j);
  }

  // ---- stage q = head + relemb[relid[b]]  (32 rows x 32 float4, fused) ----
#pragma unroll
  for (int m = 0; m < 4; ++m) {
    int k = tid + m * 256;                   // 0..1023
    int r = k >> 5, g = k & 31;
    int b = b0 + r;
    int rid = relid[b];
    float4 h = *reinterpret_cast<const float4*>(&head[b * DIM + g * 4]);
    float4 e = *reinterpret_cast<const float4*>(&relemb[rid * DIM + g * 4]);
    float4 v;
    v.x = h.x + e.x; v.y = h.y + e.y; v.z = h.z + e.z; v.w = h.w + e.w;
    *reinterpret_cast<float4*>(&lq[r * PADR + g * 4]) = v;
  }
  __syncthreads();

  float acc[8][8];
#pragma unroll
  for (int r = 0; r < 8; ++r)
#pragma unroll
    for (int k = 0; k < 8; ++k) acc[r][k] = 0.f;

  const float* lqw = lq + (w * 8) * PADR;    // wave's 8 q-rows

#pragma unroll
  for (int p = 0; p < 2; ++p) {
    if (p == 1) {
      // reload tf for m = {2,3} (serial reload; ~300cy once per wave)
#pragma unroll
      for (int k = 0; k < 8; ++k) {
#pragma unroll
        for (int j = 0; j < 2; ++j)
          tf[k][j] = *reinterpret_cast<const float4*>(tbase + (size_t)(8 * k) * DIM + 32 * (2 + j));
      }
    }
#pragma unroll
    for (int r = 0; r < 8; ++r) {
      float4 q0 = *reinterpret_cast<const float4*>(&lqw[r * PADR + (8 * (2 * p + 0) + dg) * 4]);
      float4 q1 = *reinterpret_cast<const float4*>(&lqw[r * PADR + (8 * (2 * p + 1) + dg) * 4]);
#pragma unroll
      for (int k = 0; k < 8; ++k) {
        float s = acc[r][k];
        s += fabsf(q0.x - tf[k][0].x);
        s += fabsf(q0.y - tf[k][0].y);
        s += fabsf(q0.z - tf[k][0].z);
        s += fabsf(q0.w - tf[k][0].w);
        s += fabsf(q1.x - tf[k][1].x);
        s += fabsf(q1.y - tf[k][1].y);
        s += fabsf(q1.z - tf[k][1].z);
        s += fabsf(q1.w - tf[k][1].w);
        acc[r][k] = s;
      }
    }
  }

  // ---- routed reduction across dg (masks 8/16 via ds_swizzle, 32 via shfl) ----
  const int brow = b0 + w * 8 + dg;
#pragma unroll
  for (int k = 0; k < 8; ++k) {
    float s4[4];
#pragma unroll
    for (int i = 0; i < 4; ++i) {
      float a  = acc[2 * i][k], b = acc[2 * i + 1][k];
      float xa = swz8(a), xb = swz8(b);
      s4[i] = (dg & 1) ? (b + xb) : (a + xa);       // keep rows with r0 == dg0
    }
    float s2[2];
#pragma unroll
    for (int i = 0; i < 2; ++i) {
      float a  = s4[2 * i], b = s4[2 * i + 1];
      float xa = swz16(a), xb = swz16(b);
      s2[i] = (dg & 2) ? (b + xb) : (a + xa);       // keep rows with r1 == dg1
    }
    float a  = s2[0], b = s2[1];
    float xa = __shfl_xor(a, 32), xb = __shfl_xor(b, 32);
    float v  = (dg & 4) ? (b + xb) : (a + xa);      // row r2 == dg2 -> row = dg
    out[(size_t)brow * NNEG + t0 + 8 * k + tg] = -v;
  }
}

extern "C" void kernel_launch(void* const* d_in, const int* in_sizes, int n_in,
                              void* d_out, int out_size, void* d_ws, size_t ws_size,
                              hipStream_t stream) {
  const float* head   = (const float*)d_in[0];
  const int*   relid  = (const int*)d_in[1];
  const float* tailp  = (const float*)d_in[2];
  const float* relemb = (const float*)d_in[3];
  float*       out    = (float*)d_out;

  transe_l1<<<dim3(512), dim3(256), 0, stream>>>(head, relid, tailp, relemb, out);
}